// Round 9
// baseline (5356.248 us; speedup 1.0000x reference)
//
#include <hip/hip_runtime.h>
#include <hip/hip_bf16.h>

#define D_MODEL 256
#define N_LAYER 16
#define VOCAB 24
#define D_INNER 512
#define D_STATE 16
#define D_CONV 4
#define DT_RANK 16
#define BATCH 2
#define SEQ 2048
#define NTOK (BATCH*SEQ)   /* 4096 */
#define EPS 1e-5f
#define NC 32              /* chunks per sequence */
#define CL 64              /* timesteps per chunk = wave width */
#define NSC (BATCH*D_INNER*D_STATE)      /* 16384 scan chains */

__device__ __forceinline__ float silu(float v) { return v / (1.f + __expf(-v)); }

// ---------------------------------------------------------------- embedding
__global__ void k_embed(const int* __restrict__ ids, const float* __restrict__ emb,
                        float* __restrict__ residual) {
    int idx = blockIdx.x * 256 + threadIdx.x;      // NTOK*256
    int tok = idx >> 8, c = idx & 255;
    residual[idx] = emb[ids[tok] * D_MODEL + c];
}

// ---------------------------------------------------------------- rmsnorm
__global__ void k_rmsnorm(const float* __restrict__ residual, const float* __restrict__ w,
                          float* __restrict__ hn) {
    __shared__ float red[256];
    int tok = blockIdx.x, c = threadIdx.x;
    float v = residual[tok * 256 + c];
    red[c] = v * v;
    __syncthreads();
    for (int st = 128; st > 0; st >>= 1) {
        if (c < st) red[c] += red[c + st];
        __syncthreads();
    }
    float scale = rsqrtf(red[0] * (1.f / 256.f) + EPS);
    hn[tok * 256 + c] = v * scale * w[c];
}

// ------- gemm1: [NTOK,256] @ [1024,256]^T, transposed epilogue -> x_t, z_t
__global__ __launch_bounds__(256) void k_gemm1(const float* __restrict__ A,
                                               const float* __restrict__ W,
                                               float* __restrict__ x_t,
                                               float* __restrict__ z_t) {
    __shared__ __align__(16) float As[16][68];   // stride 68: 2-way stores, 16B-aligned rows
    __shared__ __align__(16) float Ws[16][68];
    const int bm = blockIdx.x * 64, bn = blockIdx.y * 64;
    const int tid = threadIdx.x;
    const int tx = tid & 15, ty = tid >> 4;
    const int lm = tid >> 2;         // 0..63
    const int lk = (tid & 3) * 4;    // 0,4,8,12
    float acc[4][4] = {};
    for (int k0 = 0; k0 < 256; k0 += 16) {
        float4 av = *(const float4*)(A + (size_t)(bm + lm) * 256 + k0 + lk);
        float4 wv = *(const float4*)(W + (size_t)(bn + lm) * 256 + k0 + lk);
        __syncthreads();
        As[lk + 0][lm] = av.x; As[lk + 1][lm] = av.y;
        As[lk + 2][lm] = av.z; As[lk + 3][lm] = av.w;
        Ws[lk + 0][lm] = wv.x; Ws[lk + 1][lm] = wv.y;
        Ws[lk + 2][lm] = wv.z; Ws[lk + 3][lm] = wv.w;
        __syncthreads();
        #pragma unroll
        for (int kk = 0; kk < 16; kk++) {
            float4 a = *(const float4*)&As[kk][ty * 4];
            float4 b = *(const float4*)&Ws[kk][tx * 4];
            acc[0][0] += a.x * b.x; acc[0][1] += a.x * b.y; acc[0][2] += a.x * b.z; acc[0][3] += a.x * b.w;
            acc[1][0] += a.y * b.x; acc[1][1] += a.y * b.y; acc[1][2] += a.y * b.z; acc[1][3] += a.y * b.w;
            acc[2][0] += a.z * b.x; acc[2][1] += a.z * b.y; acc[2][2] += a.z * b.z; acc[2][3] += a.z * b.w;
            acc[3][0] += a.w * b.x; acc[3][1] += a.w * b.y; acc[3][2] += a.w * b.z; acc[3][3] += a.w * b.w;
        }
    }
    // transposed epilogue: column j of this thread's 4x4 = 4 consecutive tok
    int m4 = bm + ty * 4;
    #pragma unroll
    for (int j = 0; j < 4; j++) {
        int col = bn + tx * 4 + j;
        float4 v = make_float4(acc[0][j], acc[1][j], acc[2][j], acc[3][j]);
        if (bn < 512) *(float4*)(x_t + (size_t)col * NTOK + m4) = v;
        else          *(float4*)(z_t + (size_t)(col - 512) * NTOK + m4) = v;
    }
}

// ------- gemm2: residual += y @ out_w^T; A read from y_t ([k][m]-major)
__global__ __launch_bounds__(256) void k_gemm2(const float* __restrict__ y_t,
                                               const float* __restrict__ W,
                                               float* __restrict__ residual) {
    __shared__ __align__(16) float As[16][68];
    __shared__ __align__(16) float Ws[16][68];
    const int bm = blockIdx.x * 64, bn = blockIdx.y * 64;
    const int tid = threadIdx.x;
    const int tx = tid & 15, ty = tid >> 4;
    const int kt = tid >> 4;         // 0..15
    const int m4 = (tid & 15) * 4;   // 0..60
    const int lm = tid >> 2;
    const int lk = (tid & 3) * 4;
    float acc[4][4] = {};
    for (int k0 = 0; k0 < 512; k0 += 16) {
        float4 av = *(const float4*)(y_t + (size_t)(k0 + kt) * NTOK + bm + m4);  // no transpose needed
        float4 wv = *(const float4*)(W + (size_t)(bn + lm) * 512 + k0 + lk);
        __syncthreads();
        *(float4*)&As[kt][m4] = av;
        Ws[lk + 0][lm] = wv.x; Ws[lk + 1][lm] = wv.y;
        Ws[lk + 2][lm] = wv.z; Ws[lk + 3][lm] = wv.w;
        __syncthreads();
        #pragma unroll
        for (int kk = 0; kk < 16; kk++) {
            float4 a = *(const float4*)&As[kk][ty * 4];
            float4 b = *(const float4*)&Ws[kk][tx * 4];
            acc[0][0] += a.x * b.x; acc[0][1] += a.x * b.y; acc[0][2] += a.x * b.z; acc[0][3] += a.x * b.w;
            acc[1][0] += a.y * b.x; acc[1][1] += a.y * b.y; acc[1][2] += a.y * b.z; acc[1][3] += a.y * b.w;
            acc[2][0] += a.z * b.x; acc[2][1] += a.z * b.y; acc[2][2] += a.z * b.z; acc[2][3] += a.z * b.w;
            acc[3][0] += a.w * b.x; acc[3][1] += a.w * b.y; acc[3][2] += a.w * b.z; acc[3][3] += a.w * b.w;
        }
    }
    #pragma unroll
    for (int i = 0; i < 4; i++) {
        size_t row = (size_t)(bm + ty * 4 + i);
        float4* p = (float4*)(residual + row * 256 + bn + tx * 4);
        float4 r = *p;
        r.x += acc[i][0]; r.y += acc[i][1]; r.z += acc[i][2]; r.w += acc[i][3];
        *p = r;
    }
}

// ---------------- depthwise conv + silu, t-major: x_t[d][tok] -> xc_t[d][tok]
__global__ void k_conv(const float* __restrict__ x_t, const float* __restrict__ cw,
                       const float* __restrict__ cb, float* __restrict__ xc_t) {
    int idx = blockIdx.x * 256 + threadIdx.x;      // 512*4096
    int d = idx >> 12, tok = idx & 4095;
    int l = tok & 2047;
    float4 cwv = *(const float4*)(cw + d * 4);
    const float* base = x_t + (size_t)d * NTOK + tok;
    float acc = cb[d];
    if (l >= 3) acc += base[-3] * cwv.x;
    if (l >= 2) acc += base[-2] * cwv.y;
    if (l >= 1) acc += base[-1] * cwv.z;
    acc += base[0] * cwv.w;
    xc_t[idx] = silu(acc);
}

// ---------------- x_proj tiled: dbc_t[48][NTOK] = (xc @ xw^T)^T, A from xc_t
__global__ __launch_bounds__(256) void k_xproj(const float* __restrict__ xc_t,
                                               const float* __restrict__ xw,
                                               float* __restrict__ dbc_t) {
    __shared__ __align__(16) float As[16][68];
    __shared__ __align__(16) float Ws[16][52];
    const int bm = blockIdx.x * 64;
    const int tid = threadIdx.x;
    const int kt = tid >> 4, m4 = (tid & 15) * 4;
    const int mg = tid & 15, ng = tid >> 4;        // compute mapping (tid<192)
    float acc[4][4] = {};
    for (int k0 = 0; k0 < 512; k0 += 16) {
        float4 av = *(const float4*)(xc_t + (size_t)(k0 + kt) * NTOK + bm + m4);
        float4 wv = make_float4(0.f, 0.f, 0.f, 0.f);
        if (tid < 192) {
            int n = tid >> 2, k4 = (tid & 3) * 4;
            wv = *(const float4*)(xw + (size_t)n * 512 + k0 + k4);
        }
        __syncthreads();
        *(float4*)&As[kt][m4] = av;
        if (tid < 192) {
            int n = tid >> 2, k4 = (tid & 3) * 4;
            Ws[k4 + 0][n] = wv.x; Ws[k4 + 1][n] = wv.y;
            Ws[k4 + 2][n] = wv.z; Ws[k4 + 3][n] = wv.w;
        }
        __syncthreads();
        if (ng < 12) {
            #pragma unroll
            for (int kk = 0; kk < 16; kk++) {
                float4 a = *(const float4*)&As[kk][mg * 4];
                float b0 = Ws[kk][ng * 4 + 0], b1 = Ws[kk][ng * 4 + 1];
                float b2 = Ws[kk][ng * 4 + 2], b3 = Ws[kk][ng * 4 + 3];
                acc[0][0] += a.x * b0; acc[0][1] += a.x * b1; acc[0][2] += a.x * b2; acc[0][3] += a.x * b3;
                acc[1][0] += a.y * b0; acc[1][1] += a.y * b1; acc[1][2] += a.y * b2; acc[1][3] += a.y * b3;
                acc[2][0] += a.z * b0; acc[2][1] += a.z * b1; acc[2][2] += a.z * b2; acc[2][3] += a.z * b3;
                acc[3][0] += a.w * b0; acc[3][1] += a.w * b1; acc[3][2] += a.w * b2; acc[3][3] += a.w * b3;
            }
        }
    }
    if (ng < 12) {
        #pragma unroll
        for (int j = 0; j < 4; j++) {
            float4 v = make_float4(acc[0][j], acc[1][j], acc[2][j], acc[3][j]);
            *(float4*)(dbc_t + (size_t)(ng * 4 + j) * NTOK + bm + mg * 4) = v;
        }
    }
}

// ---------------- dt_t[d][tok] = softplus(dbc[:16]^T dtw[d] + dtb[d]), tiled
__global__ __launch_bounds__(256) void k_dt(const float* __restrict__ dbc_t,
                                            const float* __restrict__ dtw,
                                            const float* __restrict__ dtb,
                                            float* __restrict__ dt_t) {
    __shared__ float dtwS[64][17];
    __shared__ float dbcS[16][64];
    const int tok0 = blockIdx.x * 64, d0 = blockIdx.y * 64;
    const int tid = threadIdx.x;
    {   // stage dtw tile 64x16
        int dl = tid >> 2, r4 = (tid & 3) * 4;
        float4 w = *(const float4*)(dtw + (size_t)(d0 + dl) * 16 + r4);
        dtwS[dl][r4 + 0] = w.x; dtwS[dl][r4 + 1] = w.y;
        dtwS[dl][r4 + 2] = w.z; dtwS[dl][r4 + 3] = w.w;
    }
    {   // stage dbc rows 0..15 x 64 tok
        #pragma unroll
        for (int rr = 0; rr < 4; rr++) {
            int idx = rr * 256 + tid;
            int r = idx >> 6, t = idx & 63;
            dbcS[r][t] = dbc_t[(size_t)r * NTOK + tok0 + t];
        }
    }
    __syncthreads();
    int dl = tid >> 2, tq = tid & 3;
    float bdt = dtb[d0 + dl];
    float vals[16];
    #pragma unroll
    for (int j = 0; j < 16; j++) {
        int t = tq * 16 + j;
        float acc = bdt;
        #pragma unroll
        for (int r = 0; r < 16; r++) acc += dbcS[r][t] * dtwS[dl][r];
        vals[j] = (acc > 20.f) ? acc : __logf(1.f + __expf(acc));
    }
    float* dst = dt_t + (size_t)(d0 + dl) * NTOK + tok0 + tq * 16;
    #pragma unroll
    for (int q = 0; q < 4; q++)
        *(float4*)(dst + q * 4) = make_float4(vals[q*4], vals[q*4+1], vals[q*4+2], vals[q*4+3]);
}

// ---------------- scan phase A: wave-parallel chunk scan -> summaries
// block: 1024 thr = 16 s-waves x 64 t-lanes; grid: (b,d) x chunk = 32768
__global__ __launch_bounds__(1024) void k_scanA(const float* __restrict__ dt_t,
                                                const float* __restrict__ xc_t,
                                                const float* __restrict__ dbc_t,
                                                const float* __restrict__ a_log,
                                                float* __restrict__ Aprod,
                                                float* __restrict__ Hfin) {
    __shared__ float dtS[64], xS[64], BS[16][64];
    const int bx = blockIdx.x;
    const int c = bx & 31, bd = bx >> 5;           // bd = b*512+d
    const int d = bd & 511, b = bd >> 9;
    const int tid = threadIdx.x;
    const int s = tid >> 6, t = tid & 63;
    const int tok0 = b * SEQ + c * CL;
    if (tid < 64) dtS[tid] = dt_t[(size_t)d * NTOK + tok0 + tid];
    else if (tid < 128) xS[tid - 64] = xc_t[(size_t)d * NTOK + tok0 + (tid - 64)];
    BS[s][t] = dbc_t[(size_t)(16 + s) * NTOK + tok0 + t];
    __syncthreads();
    float As = -__expf(a_log[d * 16 + s]);
    float dtv = dtS[t], xv = xS[t];
    float a = __expf(dtv * As);
    float bb = dtv * BS[s][t] * xv;
    #pragma unroll
    for (int off = 1; off < 64; off <<= 1) {
        float aa = __shfl_up(a, off);
        float bu = __shfl_up(bb, off);
        if (t >= off) { bb = fmaf(a, bu, bb); a *= aa; }
    }
    if (t == 63) {
        int chain = (bd << 4) + s;
        Aprod[c * NSC + chain] = a;
        Hfin[c * NSC + chain] = bb;
    }
}

// ---------------- scan phase B: serial combine over chunks (in place)
__global__ void k_scanB(const float* __restrict__ Aprod, float* __restrict__ Hfin) {
    int chain = blockIdx.x * 256 + threadIdx.x;    // NSC
    float h = 0.f;
    for (int c = 0; c < NC; c++) {
        int i = c * NSC + chain;
        float a = Aprod[i], f = Hfin[i];
        Hfin[i] = h;
        h = a * h + f;
    }
}

// ---------------- scan phase C: rescan + apply start, s-reduce, gate -> y_t
__global__ __launch_bounds__(1024) void k_scanC(const float* __restrict__ dt_t,
                                                const float* __restrict__ xc_t,
                                                const float* __restrict__ z_t,
                                                const float* __restrict__ dbc_t,
                                                const float* __restrict__ a_log,
                                                const float* __restrict__ Dp,
                                                const float* __restrict__ Hstart,
                                                float* __restrict__ y_t) {
    __shared__ float dtS[64], xS[64], BS[16][64], CS[16][64], redS[16][64];
    const int bx = blockIdx.x;
    const int c = bx & 31, bd = bx >> 5;
    const int d = bd & 511, b = bd >> 9;
    const int tid = threadIdx.x;
    const int s = tid >> 6, t = tid & 63;
    const int tok0 = b * SEQ + c * CL;
    if (tid < 64) dtS[tid] = dt_t[(size_t)d * NTOK + tok0 + tid];
    else if (tid < 128) xS[tid - 64] = xc_t[(size_t)d * NTOK + tok0 + (tid - 64)];
    BS[s][t] = dbc_t[(size_t)(16 + s) * NTOK + tok0 + t];
    CS[s][t] = dbc_t[(size_t)(32 + s) * NTOK + tok0 + t];
    __syncthreads();
    float As = -__expf(a_log[d * 16 + s]);
    float dtv = dtS[t], xv = xS[t];
    float a = __expf(dtv * As);
    float bb = dtv * BS[s][t] * xv;
    #pragma unroll
    for (int off = 1; off < 64; off <<= 1) {
        float aa = __shfl_up(a, off);
        float bu = __shfl_up(bb, off);
        if (t >= off) { bb = fmaf(a, bu, bb); a *= aa; }
    }
    float h0 = Hstart[c * NSC + (bd << 4) + s];
    float h = fmaf(a, h0, bb);
    redS[s][t] = h * CS[s][t];
    __syncthreads();
    if (tid < 64) {
        float sum = 0.f;
        #pragma unroll
        for (int ss = 0; ss < 16; ss++) sum += redS[ss][tid];
        float Dv = Dp[d];
        float zv = z_t[(size_t)d * NTOK + tok0 + tid];
        y_t[(size_t)d * NTOK + tok0 + tid] = (sum + Dv * xS[tid]) * silu(zv);
    }
}

// ---------------------------------------------------------------- lm head
__global__ void k_head(const float* __restrict__ hn, const float* __restrict__ lw,
                       float* __restrict__ out) {
    int idx = blockIdx.x * 256 + threadIdx.x;      // NTOK*20 = 81920
    int tok = idx / 20, v = idx % 20;
    const float* a = hn + (size_t)tok * 256;
    const float* w = lw + (size_t)v * 256;
    float acc = 0.f;
    for (int k = 0; k < 256; k++) acc += a[k] * w[k];
    out[idx] = acc;
}

extern "C" void kernel_launch(void* const* d_in, const int* in_sizes, int n_in,
                              void* d_out, int out_size, void* d_ws, size_t ws_size,
                              hipStream_t stream) {
    const int*   ids    = (const int*)d_in[0];
    const float* emb    = (const float*)d_in[1];
    const float* in_w   = (const float*)d_in[2];
    const float* conv_w = (const float*)d_in[3];
    const float* conv_b = (const float*)d_in[4];
    const float* x_w    = (const float*)d_in[5];
    const float* dt_w   = (const float*)d_in[6];
    const float* dt_b   = (const float*)d_in[7];
    const float* a_log  = (const float*)d_in[8];
    const float* d_skip = (const float*)d_in[9];
    const float* out_w  = (const float*)d_in[10];
    const float* norm_w = (const float*)d_in[11];
    const float* norm_f = (const float*)d_in[12];
    const float* lm_w   = (const float*)d_in[13];
    float* out = (float*)d_out;

    // ---- workspace: 42,729,472 bytes (exactly the r5/r6-proven budget) ----
    char* ws = (char*)d_ws;
    float* residual = (float*)(ws + 0);            // 4 MB
    float* hn       = (float*)(ws + 4194304);      // 4 MB (aliased: Aprod/Hfin)
    float* xty      = (float*)(ws + 8388608);      // 8 MB: x_t (gemm1->conv), then y_t (scanC->gemm2)
    float* z_t      = (float*)(ws + 16777216);     // 8 MB
    float* xc_t     = (float*)(ws + 25165824);     // 8 MB
    float* dbc_t    = (float*)(ws + 33554432);     // 768 KB
    float* dt_t     = (float*)(ws + 34340864);     // 8 MB  -> end 42,729,472
    float* Aprod    = hn;                          // 2 MB
    float* Hfin     = hn + NC * NSC / 1;           // careful: NC*NSC = 524288 floats = 2 MB
    Hfin = (float*)(ws + 4194304 + 2097152);

    k_embed<<<(NTOK * 256) / 256, 256, 0, stream>>>(ids, emb, residual);

    for (int i = 0; i < N_LAYER; i++) {
        k_rmsnorm<<<NTOK, 256, 0, stream>>>(residual, norm_w + i * D_MODEL, hn);
        dim3 g1(NTOK / 64, 1024 / 64);
        k_gemm1<<<g1, 256, 0, stream>>>(hn, in_w + (size_t)i * 1024 * 256, xty, z_t);
        k_conv<<<(512 * NTOK) / 256, 256, 0, stream>>>(
            xty, conv_w + (size_t)i * 512 * 4, conv_b + (size_t)i * 512, xc_t);
        k_xproj<<<NTOK / 64, 256, 0, stream>>>(xc_t, x_w + (size_t)i * 48 * 512, dbc_t);
        dim3 gdt(NTOK / 64, 512 / 64);
        k_dt<<<gdt, 256, 0, stream>>>(dbc_t, dt_w + (size_t)i * 512 * 16,
                                      dt_b + (size_t)i * 512, dt_t);
        k_scanA<<<BATCH * 512 * NC, 1024, 0, stream>>>(
            dt_t, xc_t, dbc_t, a_log + (size_t)i * 512 * 16, Aprod, Hfin);
        k_scanB<<<NSC / 256, 256, 0, stream>>>(Aprod, Hfin);
        k_scanC<<<BATCH * 512 * NC, 1024, 0, stream>>>(
            dt_t, xc_t, z_t, dbc_t, a_log + (size_t)i * 512 * 16,
            d_skip + (size_t)i * 512, Hfin, xty);
        dim3 g2(NTOK / 64, 256 / 64);
        k_gemm2<<<g2, 256, 0, stream>>>(xty, out_w + (size_t)i * 256 * 512, residual);
    }

    k_rmsnorm<<<NTOK, 256, 0, stream>>>(residual, norm_f, hn);
    k_head<<<320, 256, 0, stream>>>(hn, lm_w, out);
}

// Round 10
// 4397.131 us; speedup vs baseline: 1.2181x; 1.2181x over previous
//
#include <hip/hip_runtime.h>
#include <hip/hip_bf16.h>

#define D_MODEL 256
#define N_LAYER 16
#define VOCAB 24
#define D_INNER 512
#define D_STATE 16
#define D_CONV 4
#define DT_RANK 16
#define BATCH 2
#define SEQ 2048
#define NTOK (BATCH*SEQ)   /* 4096 */
#define EPS 1e-5f
#define NC 32              /* scan chunks per sequence */
#define CL (SEQ/NC)        /* 64 tokens per chunk */
#define NSC (BATCH*D_INNER*D_STATE)      /* 16384 scan chains */

__device__ __forceinline__ float silu(float v) { return v / (1.f + __expf(-v)); }

// ---------------------------------------------------------------- embedding
__global__ void k_embed(const int* __restrict__ ids, const float* __restrict__ emb,
                        float* __restrict__ residual) {
    int idx = blockIdx.x * 256 + threadIdx.x;      // NTOK*256
    int tok = idx >> 8, c = idx & 255;
    residual[idx] = emb[ids[tok] * D_MODEL + c];
}

// ---------------------------------------------------------------- rmsnorm
__global__ void k_rmsnorm(const float* __restrict__ residual, const float* __restrict__ w,
                          float* __restrict__ hn) {
    __shared__ float red[256];
    int tok = blockIdx.x, c = threadIdx.x;
    float v = residual[tok * 256 + c];
    red[c] = v * v;
    __syncthreads();
    for (int st = 128; st > 0; st >>= 1) {
        if (c < st) red[c] += red[c + st];
        __syncthreads();
    }
    float scale = rsqrtf(red[0] * (1.f / 256.f) + EPS);
    hn[tok * 256 + c] = v * scale * w[c];
}

// ---------------- gemm1 tiled: [NTOK,256] @ [1024,256]^T -> split x/z
// LDS stride 68: staging 4-way conflict -> free 2-way; rows stay 16B-aligned
__global__ __launch_bounds__(256) void k_gemm1_tiled(const float* __restrict__ A,
                                                     const float* __restrict__ W,
                                                     float* __restrict__ xh,
                                                     float* __restrict__ zb) {
    __shared__ __align__(16) float As[16][68];
    __shared__ __align__(16) float Ws[16][68];
    const int bm = blockIdx.x * 64, bn = blockIdx.y * 64;
    const int tid = threadIdx.x;
    const int tx = tid & 15, ty = tid >> 4;
    const int lm = tid >> 2;         // 0..63
    const int lk = (tid & 3) * 4;    // 0,4,8,12
    float acc[4][4] = {};
    for (int k0 = 0; k0 < 256; k0 += 16) {
        float4 av = *(const float4*)(A + (size_t)(bm + lm) * 256 + k0 + lk);
        float4 wv = *(const float4*)(W + (size_t)(bn + lm) * 256 + k0 + lk);
        __syncthreads();
        As[lk + 0][lm] = av.x; As[lk + 1][lm] = av.y;
        As[lk + 2][lm] = av.z; As[lk + 3][lm] = av.w;
        Ws[lk + 0][lm] = wv.x; Ws[lk + 1][lm] = wv.y;
        Ws[lk + 2][lm] = wv.z; Ws[lk + 3][lm] = wv.w;
        __syncthreads();
        #pragma unroll
        for (int kk = 0; kk < 16; kk++) {
            float4 a = *(const float4*)&As[kk][ty * 4];
            float4 b = *(const float4*)&Ws[kk][tx * 4];
            acc[0][0] += a.x * b.x; acc[0][1] += a.x * b.y; acc[0][2] += a.x * b.z; acc[0][3] += a.x * b.w;
            acc[1][0] += a.y * b.x; acc[1][1] += a.y * b.y; acc[1][2] += a.y * b.z; acc[1][3] += a.y * b.w;
            acc[2][0] += a.z * b.x; acc[2][1] += a.z * b.y; acc[2][2] += a.z * b.z; acc[2][3] += a.z * b.w;
            acc[3][0] += a.w * b.x; acc[3][1] += a.w * b.y; acc[3][2] += a.w * b.z; acc[3][3] += a.w * b.w;
        }
    }
    #pragma unroll
    for (int i = 0; i < 4; i++) {
        size_t row = (size_t)(bm + ty * 4 + i);
        float4 v = make_float4(acc[i][0], acc[i][1], acc[i][2], acc[i][3]);
        if (bn < 512) *(float4*)(xh + row * 512 + bn + tx * 4) = v;      // uniform per block
        else          *(float4*)(zb + row * 512 + (bn - 512) + tx * 4) = v;
    }
}

// ---------------- gemm2 tiled: residual += [NTOK,512] @ [256,512]^T
__global__ __launch_bounds__(256) void k_gemm2_tiled(const float* __restrict__ A,
                                                     const float* __restrict__ W,
                                                     float* __restrict__ residual) {
    __shared__ __align__(16) float As[16][68];
    __shared__ __align__(16) float Ws[16][68];
    const int bm = blockIdx.x * 64, bn = blockIdx.y * 64;
    const int tid = threadIdx.x;
    const int tx = tid & 15, ty = tid >> 4;
    const int lm = tid >> 2;
    const int lk = (tid & 3) * 4;
    float acc[4][4] = {};
    for (int k0 = 0; k0 < 512; k0 += 16) {
        float4 av = *(const float4*)(A + (size_t)(bm + lm) * 512 + k0 + lk);
        float4 wv = *(const float4*)(W + (size_t)(bn + lm) * 512 + k0 + lk);
        __syncthreads();
        As[lk + 0][lm] = av.x; As[lk + 1][lm] = av.y;
        As[lk + 2][lm] = av.z; As[lk + 3][lm] = av.w;
        Ws[lk + 0][lm] = wv.x; Ws[lk + 1][lm] = wv.y;
        Ws[lk + 2][lm] = wv.z; Ws[lk + 3][lm] = wv.w;
        __syncthreads();
        #pragma unroll
        for (int kk = 0; kk < 16; kk++) {
            float4 a = *(const float4*)&As[kk][ty * 4];
            float4 b = *(const float4*)&Ws[kk][tx * 4];
            acc[0][0] += a.x * b.x; acc[0][1] += a.x * b.y; acc[0][2] += a.x * b.z; acc[0][3] += a.x * b.w;
            acc[1][0] += a.y * b.x; acc[1][1] += a.y * b.y; acc[1][2] += a.y * b.z; acc[1][3] += a.y * b.w;
            acc[2][0] += a.z * b.x; acc[2][1] += a.z * b.y; acc[2][2] += a.z * b.z; acc[2][3] += a.z * b.w;
            acc[3][0] += a.w * b.x; acc[3][1] += a.w * b.y; acc[3][2] += a.w * b.z; acc[3][3] += a.w * b.w;
        }
    }
    #pragma unroll
    for (int i = 0; i < 4; i++) {
        size_t row = (size_t)(bm + ty * 4 + i);
        float4* p = (float4*)(residual + row * 256 + bn + tx * 4);
        float4 r = *p;
        r.x += acc[i][0]; r.y += acc[i][1]; r.z += acc[i][2]; r.w += acc[i][3];
        *p = r;
    }
}

// ------------------------------------------------- depthwise conv + silu
__global__ void k_conv(const float* __restrict__ xh, const float* __restrict__ cw,
                       const float* __restrict__ cb, float* __restrict__ xb) {
    int idx = blockIdx.x * 256 + threadIdx.x;      // NTOK*512
    int tok = idx >> 9, d = idx & 511;
    int b = tok >> 11, l = tok & 2047;
    const float* base = xh + (size_t)(b * 2048) * 512 + d;
    float acc = cb[d];
    #pragma unroll
    for (int k = 0; k < 4; k++) {
        int t = l - 3 + k;
        if (t >= 0) acc += base[(size_t)t * 512] * cw[d * 4 + k];
    }
    xb[idx] = silu(acc);
}

// ------------------------- x_proj: block per token, LDS x row, 48 outputs
__global__ __launch_bounds__(64) void k_xproj(const float* __restrict__ xb,
                                              const float* __restrict__ xw,
                                              float* __restrict__ dbc) {
    __shared__ __align__(16) float xrow[512];
    int tok = blockIdx.x, t = threadIdx.x;
    const float* xp = xb + (size_t)tok * 512;
    #pragma unroll
    for (int i = 0; i < 8; i++) xrow[t + i * 64] = xp[t + i * 64];
    __syncthreads();
    if (t < 48) {
        const float4* w4 = (const float4*)(xw + (size_t)t * 512);
        const float4* x4 = (const float4*)xrow;
        float acc = 0.f;
        #pragma unroll 8
        for (int k4 = 0; k4 < 128; k4++) {
            float4 wv = w4[k4];
            float4 xv = x4[k4];
            acc += xv.x * wv.x + xv.y * wv.y + xv.z * wv.z + xv.w * wv.w;
        }
        dbc[(size_t)tok * 48 + t] = acc;
    }
}

// -------------------------- dt = softplus(dbc[:, :16] @ dtw^T + dtb)
__global__ void k_dt(const float* __restrict__ dbc, const float* __restrict__ dtw,
                     const float* __restrict__ dtb, float* __restrict__ dt) {
    int idx = blockIdx.x * 256 + threadIdx.x;      // NTOK*512
    int tok = idx >> 9, d = idx & 511;
    const float* row = dbc + (size_t)tok * 48;
    const float* w = dtw + d * 16;
    float acc = dtb[d];
    #pragma unroll
    for (int r = 0; r < 16; r++) acc += row[r] * w[r];
    dt[idx] = (acc > 20.f) ? acc : __logf(1.f + __expf(acc));
}

// -------- scan phase A: thread = (b,d,chunk), 16 s-states in registers
// 16 independent h-chains per thread -> ILP hides exp/fma latency
__global__ __launch_bounds__(64) void k_scanA(const float* __restrict__ dt,
                                              const float* __restrict__ xb,
                                              const float* __restrict__ dbc,
                                              const float* __restrict__ a_log,
                                              float* __restrict__ Aprod,
                                              float* __restrict__ Hfin) {
    int gid = blockIdx.x * 64 + threadIdx.x;       // 1024*NC = 32768
    int bd = gid & 1023;                           // fast index -> coalesced d
    int c = gid >> 10;
    int d = bd & 511, b = bd >> 9;
    float A[16], h[16], ap[16];
    #pragma unroll
    for (int s = 0; s < 16; s++) {
        A[s] = -__expf(a_log[d * 16 + s]);
        h[s] = 0.f; ap[s] = 1.f;
    }
    int tok0 = b * SEQ + c * CL;
    const float* dtp = dt + (size_t)tok0 * 512 + d;
    const float* xp  = xb + (size_t)tok0 * 512 + d;
    const float* rp  = dbc + (size_t)tok0 * 48;
    #pragma unroll 2
    for (int t = 0; t < CL; t++) {
        float dtv = dtp[t * 512];
        float u = dtv * xp[t * 512];
        const float4* Bp = (const float4*)(rp + t * 48 + 16);
        float Bv[16];
        *(float4*)&Bv[0]  = Bp[0]; *(float4*)&Bv[4]  = Bp[1];
        *(float4*)&Bv[8]  = Bp[2]; *(float4*)&Bv[12] = Bp[3];
        #pragma unroll
        for (int s = 0; s < 16; s++) {
            float dA = __expf(dtv * A[s]);
            h[s] = fmaf(dA, h[s], u * Bv[s]);
            ap[s] *= dA;
        }
    }
    float* Ap = Aprod + (size_t)c * NSC + bd * 16;
    float* Hp = Hfin  + (size_t)c * NSC + bd * 16;
    #pragma unroll
    for (int q = 0; q < 4; q++) {
        *(float4*)(Ap + q * 4) = make_float4(ap[q*4], ap[q*4+1], ap[q*4+2], ap[q*4+3]);
        *(float4*)(Hp + q * 4) = make_float4(h[q*4], h[q*4+1], h[q*4+2], h[q*4+3]);
    }
}

// ---------------- scan phase B: serial combine over chunks (in place)
__global__ void k_scanB(const float* __restrict__ Aprod, float* __restrict__ Hfin) {
    int chain = blockIdx.x * 256 + threadIdx.x;    // NSC
    float h = 0.f;
    for (int c = 0; c < NC; c++) {
        int i = c * NSC + chain;
        float a = Aprod[i], f = Hfin[i];
        Hfin[i] = h;
        h = a * h + f;
    }
}

// -------- scan phase C: rescan from start state, 16 s in regs, gate -> y
__global__ __launch_bounds__(64) void k_scanC(const float* __restrict__ dt,
                                              const float* __restrict__ xb,
                                              const float* __restrict__ zb,
                                              const float* __restrict__ dbc,
                                              const float* __restrict__ a_log,
                                              const float* __restrict__ Dp,
                                              const float* __restrict__ Hstart,
                                              float* __restrict__ yb) {
    int gid = blockIdx.x * 64 + threadIdx.x;       // 32768
    int bd = gid & 1023;
    int c = gid >> 10;
    int d = bd & 511, b = bd >> 9;
    float A[16], h[16];
    const float* Hp = Hstart + (size_t)c * NSC + bd * 16;
    #pragma unroll
    for (int s = 0; s < 16; s++) {
        A[s] = -__expf(a_log[d * 16 + s]);
        h[s] = Hp[s];
    }
    float Dv = Dp[d];
    int tok0 = b * SEQ + c * CL;
    const float* dtp = dt + (size_t)tok0 * 512 + d;
    const float* xp  = xb + (size_t)tok0 * 512 + d;
    const float* zp  = zb + (size_t)tok0 * 512 + d;
    const float* rp  = dbc + (size_t)tok0 * 48;
    float* yp = yb + (size_t)tok0 * 512 + d;
    #pragma unroll 2
    for (int t = 0; t < CL; t++) {
        float dtv = dtp[t * 512];
        float xv  = xp[t * 512];
        float u = dtv * xv;
        const float4* Bp = (const float4*)(rp + t * 48 + 16);
        float Bv[16], Cv[16];
        *(float4*)&Bv[0]  = Bp[0]; *(float4*)&Bv[4]  = Bp[1];
        *(float4*)&Bv[8]  = Bp[2]; *(float4*)&Bv[12] = Bp[3];
        *(float4*)&Cv[0]  = Bp[4]; *(float4*)&Cv[4]  = Bp[5];
        *(float4*)&Cv[8]  = Bp[6]; *(float4*)&Cv[12] = Bp[7];
        float sum = 0.f;
        #pragma unroll
        for (int s = 0; s < 16; s++) {
            float dA = __expf(dtv * A[s]);
            h[s] = fmaf(dA, h[s], u * Bv[s]);
            sum = fmaf(h[s], Cv[s], sum);
        }
        float zv = zp[t * 512];
        yp[t * 512] = (sum + Dv * xv) * silu(zv);
    }
}

// ---------------------------------------------------------------- lm head
__global__ void k_head(const float* __restrict__ hn, const float* __restrict__ lw,
                       float* __restrict__ out) {
    int idx = blockIdx.x * 256 + threadIdx.x;      // NTOK*20 = 81920
    int tok = idx / 20, v = idx % 20;
    const float* a = hn + (size_t)tok * 256;
    const float* w = lw + (size_t)v * 256;
    float acc = 0.f;
    for (int k = 0; k < 256; k++) acc += a[k] * w[k];
    out[idx] = acc;
}

extern "C" void kernel_launch(void* const* d_in, const int* in_sizes, int n_in,
                              void* d_out, int out_size, void* d_ws, size_t ws_size,
                              hipStream_t stream) {
    const int*   ids    = (const int*)d_in[0];
    const float* emb    = (const float*)d_in[1];
    const float* in_w   = (const float*)d_in[2];
    const float* conv_w = (const float*)d_in[3];
    const float* conv_b = (const float*)d_in[4];
    const float* x_w    = (const float*)d_in[5];
    const float* dt_w   = (const float*)d_in[6];
    const float* dt_b   = (const float*)d_in[7];
    const float* a_log  = (const float*)d_in[8];
    const float* d_skip = (const float*)d_in[9];
    const float* out_w  = (const float*)d_in[10];
    const float* norm_w = (const float*)d_in[11];
    const float* norm_f = (const float*)d_in[12];
    const float* lm_w   = (const float*)d_in[13];
    float* out = (float*)d_out;

    // ---- workspace: 42,729,472 bytes (r5/r6-proven budget) ----
    char* ws = (char*)d_ws;
    float* residual = (float*)(ws + 0);            // 4 MB
    float* hn       = (float*)(ws + 4194304);      // 4 MB (aliased: Aprod 2MB + Hfin 2MB)
    float* xh       = (float*)(ws + 8388608);      // 8 MB (aliased: yb after conv)
    float* zb       = (float*)(ws + 16777216);     // 8 MB
    float* xb       = (float*)(ws + 25165824);     // 8 MB
    float* dbc      = (float*)(ws + 33554432);     // 768 KB
    float* dt       = (float*)(ws + 34340864);     // 8 MB
    float* Aprod    = hn;                          // NC*NSC f32 = 2 MB
    float* Hfin     = (float*)(ws + 4194304 + 2097152);   // 2 MB
    float* yb       = xh;

    k_embed<<<(NTOK * 256) / 256, 256, 0, stream>>>(ids, emb, residual);

    for (int i = 0; i < N_LAYER; i++) {
        k_rmsnorm<<<NTOK, 256, 0, stream>>>(residual, norm_w + i * D_MODEL, hn);
        dim3 g1(NTOK / 64, 1024 / 64);
        k_gemm1_tiled<<<g1, 256, 0, stream>>>(hn, in_w + (size_t)i * 1024 * 256, xh, zb);
        k_conv<<<(NTOK * 512) / 256, 256, 0, stream>>>(
            xh, conv_w + (size_t)i * 512 * 4, conv_b + (size_t)i * 512, xb);
        k_xproj<<<NTOK, 64, 0, stream>>>(xb, x_w + (size_t)i * 48 * 512, dbc);
        k_dt<<<(NTOK * 512) / 256, 256, 0, stream>>>(
            dbc, dt_w + (size_t)i * 512 * 16, dt_b + (size_t)i * 512, dt);
        k_scanA<<<(1024 * NC) / 64, 64, 0, stream>>>(
            dt, xb, dbc, a_log + (size_t)i * 512 * 16, Aprod, Hfin);
        k_scanB<<<NSC / 256, 256, 0, stream>>>(Aprod, Hfin);
        k_scanC<<<(1024 * NC) / 64, 64, 0, stream>>>(
            dt, xb, zb, dbc, a_log + (size_t)i * 512 * 16,
            d_skip + (size_t)i * 512, Hfin, yb);
        dim3 g2(NTOK / 64, 256 / 64);
        k_gemm2_tiled<<<g2, 256, 0, stream>>>(yb, out_w + (size_t)i * 256 * 512, residual);
    }

    k_rmsnorm<<<NTOK, 256, 0, stream>>>(residual, norm_f, hn);
    k_head<<<320, 256, 0, stream>>>(hn, lm_w, out);
}

// Round 11
// 3054.696 us; speedup vs baseline: 1.7534x; 1.4395x over previous
//
#include <hip/hip_runtime.h>
#include <hip/hip_bf16.h>

#define D_MODEL 256
#define N_LAYER 16
#define VOCAB 24
#define D_INNER 512
#define D_STATE 16
#define D_CONV 4
#define DT_RANK 16
#define BATCH 2
#define SEQ 2048
#define NTOK (BATCH*SEQ)   /* 4096 */
#define EPS 1e-5f
#define NC 64              /* scan chunks per sequence */
#define CL (SEQ/NC)        /* 32 tokens per chunk */
#define NSC (BATCH*D_INNER*D_STATE)      /* 16384 scan chains */

__device__ __forceinline__ float silu(float v) { return v / (1.f + __expf(-v)); }

// ---------------------------------------------------------------- embedding
__global__ void k_embed(const int* __restrict__ ids, const float* __restrict__ emb,
                        float* __restrict__ residual) {
    int idx = blockIdx.x * 256 + threadIdx.x;      // NTOK*256
    int tok = idx >> 8, c = idx & 255;
    residual[idx] = emb[ids[tok] * D_MODEL + c];
}

// ---------------------------------------------------------------- rmsnorm
__global__ void k_rmsnorm(const float* __restrict__ residual, const float* __restrict__ w,
                          float* __restrict__ hn) {
    __shared__ float red[256];
    int tok = blockIdx.x, c = threadIdx.x;
    float v = residual[tok * 256 + c];
    red[c] = v * v;
    __syncthreads();
    for (int st = 128; st > 0; st >>= 1) {
        if (c < st) red[c] += red[c + st];
        __syncthreads();
    }
    float scale = rsqrtf(red[0] * (1.f / 256.f) + EPS);
    hn[tok * 256 + c] = v * scale * w[c];
}

// ---------------- gemm1 tiled: [NTOK,256] @ [1024,256]^T -> split x/z
__global__ __launch_bounds__(256) void k_gemm1_tiled(const float* __restrict__ A,
                                                     const float* __restrict__ W,
                                                     float* __restrict__ xh,
                                                     float* __restrict__ zb) {
    __shared__ __align__(16) float As[16][68];
    __shared__ __align__(16) float Ws[16][68];
    const int bm = blockIdx.x * 64, bn = blockIdx.y * 64;
    const int tid = threadIdx.x;
    const int tx = tid & 15, ty = tid >> 4;
    const int lm = tid >> 2;         // 0..63
    const int lk = (tid & 3) * 4;    // 0,4,8,12
    float acc[4][4] = {};
    for (int k0 = 0; k0 < 256; k0 += 16) {
        float4 av = *(const float4*)(A + (size_t)(bm + lm) * 256 + k0 + lk);
        float4 wv = *(const float4*)(W + (size_t)(bn + lm) * 256 + k0 + lk);
        __syncthreads();
        As[lk + 0][lm] = av.x; As[lk + 1][lm] = av.y;
        As[lk + 2][lm] = av.z; As[lk + 3][lm] = av.w;
        Ws[lk + 0][lm] = wv.x; Ws[lk + 1][lm] = wv.y;
        Ws[lk + 2][lm] = wv.z; Ws[lk + 3][lm] = wv.w;
        __syncthreads();
        #pragma unroll
        for (int kk = 0; kk < 16; kk++) {
            float4 a = *(const float4*)&As[kk][ty * 4];
            float4 b = *(const float4*)&Ws[kk][tx * 4];
            acc[0][0] += a.x * b.x; acc[0][1] += a.x * b.y; acc[0][2] += a.x * b.z; acc[0][3] += a.x * b.w;
            acc[1][0] += a.y * b.x; acc[1][1] += a.y * b.y; acc[1][2] += a.y * b.z; acc[1][3] += a.y * b.w;
            acc[2][0] += a.z * b.x; acc[2][1] += a.z * b.y; acc[2][2] += a.z * b.z; acc[2][3] += a.z * b.w;
            acc[3][0] += a.w * b.x; acc[3][1] += a.w * b.y; acc[3][2] += a.w * b.z; acc[3][3] += a.w * b.w;
        }
    }
    #pragma unroll
    for (int i = 0; i < 4; i++) {
        size_t row = (size_t)(bm + ty * 4 + i);
        float4 v = make_float4(acc[i][0], acc[i][1], acc[i][2], acc[i][3]);
        if (bn < 512) *(float4*)(xh + row * 512 + bn + tx * 4) = v;      // uniform per block
        else          *(float4*)(zb + row * 512 + (bn - 512) + tx * 4) = v;
    }
}

// ---------------- gemm2 tiled: residual += [NTOK,512] @ [256,512]^T
__global__ __launch_bounds__(256) void k_gemm2_tiled(const float* __restrict__ A,
                                                     const float* __restrict__ W,
                                                     float* __restrict__ residual) {
    __shared__ __align__(16) float As[16][68];
    __shared__ __align__(16) float Ws[16][68];
    const int bm = blockIdx.x * 64, bn = blockIdx.y * 64;
    const int tid = threadIdx.x;
    const int tx = tid & 15, ty = tid >> 4;
    const int lm = tid >> 2;
    const int lk = (tid & 3) * 4;
    float acc[4][4] = {};
    for (int k0 = 0; k0 < 512; k0 += 16) {
        float4 av = *(const float4*)(A + (size_t)(bm + lm) * 512 + k0 + lk);
        float4 wv = *(const float4*)(W + (size_t)(bn + lm) * 512 + k0 + lk);
        __syncthreads();
        As[lk + 0][lm] = av.x; As[lk + 1][lm] = av.y;
        As[lk + 2][lm] = av.z; As[lk + 3][lm] = av.w;
        Ws[lk + 0][lm] = wv.x; Ws[lk + 1][lm] = wv.y;
        Ws[lk + 2][lm] = wv.z; Ws[lk + 3][lm] = wv.w;
        __syncthreads();
        #pragma unroll
        for (int kk = 0; kk < 16; kk++) {
            float4 a = *(const float4*)&As[kk][ty * 4];
            float4 b = *(const float4*)&Ws[kk][tx * 4];
            acc[0][0] += a.x * b.x; acc[0][1] += a.x * b.y; acc[0][2] += a.x * b.z; acc[0][3] += a.x * b.w;
            acc[1][0] += a.y * b.x; acc[1][1] += a.y * b.y; acc[1][2] += a.y * b.z; acc[1][3] += a.y * b.w;
            acc[2][0] += a.z * b.x; acc[2][1] += a.z * b.y; acc[2][2] += a.z * b.z; acc[2][3] += a.z * b.w;
            acc[3][0] += a.w * b.x; acc[3][1] += a.w * b.y; acc[3][2] += a.w * b.z; acc[3][3] += a.w * b.w;
        }
    }
    #pragma unroll
    for (int i = 0; i < 4; i++) {
        size_t row = (size_t)(bm + ty * 4 + i);
        float4* p = (float4*)(residual + row * 256 + bn + tx * 4);
        float4 r = *p;
        r.x += acc[i][0]; r.y += acc[i][1]; r.z += acc[i][2]; r.w += acc[i][3];
        *p = r;
    }
}

// ------------- fused depthwise conv + silu + x_proj (16 tokens per block)
// conv result staged in LDS (and written to xb for the scan); then 48-dim
// x_proj per token computed from LDS, cutting x_w re-reads 16x.
__global__ __launch_bounds__(256) void k_convxproj(const float* __restrict__ xh,
                                                   const float* __restrict__ cw,
                                                   const float* __restrict__ cb,
                                                   const float* __restrict__ xw,
                                                   float* __restrict__ xb,
                                                   float* __restrict__ dbc) {
    __shared__ __align__(16) float xcS[16][516];   // pad 4: spreads row base banks
    const int tok0 = blockIdx.x * 16;              // 16 | 2048 -> no batch crossing
    const int b = tok0 >> 11, l0 = tok0 & 2047;
    const int tid = threadIdx.x;
    // ---- conv: sliding window along t, 2 d-values per thread
    #pragma unroll
    for (int dstep = 0; dstep < 2; dstep++) {
        int d = tid + dstep * 256;
        float4 cwv = *(const float4*)(cw + d * 4);
        float cbv = cb[d];
        const float* base = xh + ((size_t)(b << 11)) * 512 + d;
        float xv[19];
        #pragma unroll
        for (int i = 0; i < 19; i++) {
            int lt = l0 - 3 + i;
            xv[i] = (lt >= 0) ? base[(size_t)lt * 512] : 0.f;
        }
        #pragma unroll
        for (int t = 0; t < 16; t++) {
            float acc = cbv + xv[t] * cwv.x + xv[t+1] * cwv.y + xv[t+2] * cwv.z + xv[t+3] * cwv.w;
            float v = silu(acc);
            xcS[t][d] = v;
            xb[(size_t)(tok0 + t) * 512 + d] = v;
        }
    }
    __syncthreads();
    // ---- x_proj: thread (tokg, l) computes e = l, l+16, l+32 for its token
    const int tokg = tid >> 4, l = tid & 15;
    #pragma unroll
    for (int j = 0; j < 3; j++) {
        int e = l + j * 16;
        const float4* w4 = (const float4*)(xw + (size_t)e * 512);
        const float4* x4 = (const float4*)&xcS[tokg][0];
        float acc = 0.f;
        #pragma unroll 8
        for (int k4 = 0; k4 < 128; k4++) {
            float4 wv = w4[k4];
            float4 xv = x4[k4];
            acc += xv.x * wv.x + xv.y * wv.y + xv.z * wv.z + xv.w * wv.w;
        }
        dbc[(size_t)(tok0 + tokg) * 48 + e] = acc;
    }
}

// -------- scan phase A: thread = (b,d,chunk); dt_proj+softplus fused;
// 16 s-states in registers (ILP); dbc row broadcast across the wave.
__global__ __launch_bounds__(64) void k_scanA(const float* __restrict__ xb,
                                              const float* __restrict__ dbc,
                                              const float* __restrict__ dtw,
                                              const float* __restrict__ dtb,
                                              const float* __restrict__ a_log,
                                              float* __restrict__ Aprod,
                                              float* __restrict__ Hfin) {
    int gid = blockIdx.x * 64 + threadIdx.x;       // 1024*NC = 65536
    int bd = gid & 1023;                           // fast index -> coalesced d
    int c = gid >> 10;
    int d = bd & 511, b = bd >> 9;
    float A[16], h[16], ap[16], wdt[16];
    #pragma unroll
    for (int q = 0; q < 4; q++)
        *(float4*)&wdt[q*4] = *(const float4*)(dtw + d * 16 + q * 4);
    #pragma unroll
    for (int s = 0; s < 16; s++) {
        A[s] = -__expf(a_log[d * 16 + s]);
        h[s] = 0.f; ap[s] = 1.f;
    }
    float bdt = dtb[d];
    int tok0 = b * SEQ + c * CL;
    const float* xp = xb + (size_t)tok0 * 512 + d;
    const float* rp = dbc + (size_t)tok0 * 48;
    for (int t = 0; t < CL; t++) {
        float rv[32];
        #pragma unroll
        for (int q = 0; q < 8; q++) *(float4*)&rv[q*4] = *(const float4*)(rp + t * 48 + q * 4);
        float dtr = bdt;
        #pragma unroll
        for (int r = 0; r < 16; r++) dtr = fmaf(rv[r], wdt[r], dtr);
        float dtv = (dtr > 20.f) ? dtr : __logf(1.f + __expf(dtr));
        float u = dtv * xp[t * 512];
        #pragma unroll
        for (int s = 0; s < 16; s++) {
            float dA = __expf(dtv * A[s]);
            h[s] = fmaf(dA, h[s], u * rv[16 + s]);
            ap[s] *= dA;
        }
    }
    float* Ap = Aprod + (size_t)c * NSC + bd * 16;
    float* Hp = Hfin  + (size_t)c * NSC + bd * 16;
    #pragma unroll
    for (int q = 0; q < 4; q++) {
        *(float4*)(Ap + q * 4) = make_float4(ap[q*4], ap[q*4+1], ap[q*4+2], ap[q*4+3]);
        *(float4*)(Hp + q * 4) = make_float4(h[q*4], h[q*4+1], h[q*4+2], h[q*4+3]);
    }
}

// ---------------- scan phase B: serial combine over chunks (in place)
__global__ void k_scanB(const float* __restrict__ Aprod, float* __restrict__ Hfin) {
    int chain = blockIdx.x * 256 + threadIdx.x;    // NSC
    float h = 0.f;
    for (int c = 0; c < NC; c++) {
        int i = c * NSC + chain;
        float a = Aprod[i], f = Hfin[i];
        Hfin[i] = h;
        h = a * h + f;
    }
}

// -------- scan phase C: rescan from start state (dt fused), gate -> y
__global__ __launch_bounds__(64) void k_scanC(const float* __restrict__ xb,
                                              const float* __restrict__ zb,
                                              const float* __restrict__ dbc,
                                              const float* __restrict__ dtw,
                                              const float* __restrict__ dtb,
                                              const float* __restrict__ a_log,
                                              const float* __restrict__ Dp,
                                              const float* __restrict__ Hstart,
                                              float* __restrict__ yb) {
    int gid = blockIdx.x * 64 + threadIdx.x;       // 65536
    int bd = gid & 1023;
    int c = gid >> 10;
    int d = bd & 511, b = bd >> 9;
    float A[16], h[16], wdt[16];
    #pragma unroll
    for (int q = 0; q < 4; q++)
        *(float4*)&wdt[q*4] = *(const float4*)(dtw + d * 16 + q * 4);
    const float* Hp = Hstart + (size_t)c * NSC + bd * 16;
    #pragma unroll
    for (int s = 0; s < 16; s++) {
        A[s] = -__expf(a_log[d * 16 + s]);
        h[s] = Hp[s];
    }
    float bdt = dtb[d];
    float Dv = Dp[d];
    int tok0 = b * SEQ + c * CL;
    const float* xp = xb + (size_t)tok0 * 512 + d;
    const float* zp = zb + (size_t)tok0 * 512 + d;
    const float* rp = dbc + (size_t)tok0 * 48;
    float* yp = yb + (size_t)tok0 * 512 + d;
    for (int t = 0; t < CL; t++) {
        float rv[48];
        #pragma unroll
        for (int q = 0; q < 12; q++) *(float4*)&rv[q*4] = *(const float4*)(rp + t * 48 + q * 4);
        float dtr = bdt;
        #pragma unroll
        for (int r = 0; r < 16; r++) dtr = fmaf(rv[r], wdt[r], dtr);
        float dtv = (dtr > 20.f) ? dtr : __logf(1.f + __expf(dtr));
        float xv = xp[t * 512];
        float u = dtv * xv;
        float sum = 0.f;
        #pragma unroll
        for (int s = 0; s < 16; s++) {
            float dA = __expf(dtv * A[s]);
            h[s] = fmaf(dA, h[s], u * rv[16 + s]);
            sum = fmaf(h[s], rv[32 + s], sum);
        }
        float zv = zp[t * 512];
        yp[t * 512] = (sum + Dv * xv) * silu(zv);
    }
}

// ---------------------------------------------------------------- lm head
__global__ void k_head(const float* __restrict__ hn, const float* __restrict__ lw,
                       float* __restrict__ out) {
    int idx = blockIdx.x * 256 + threadIdx.x;      // NTOK*20 = 81920
    int tok = idx / 20, v = idx % 20;
    const float* a = hn + (size_t)tok * 256;
    const float* w = lw + (size_t)v * 256;
    float acc = 0.f;
    for (int k = 0; k < 256; k++) acc += a[k] * w[k];
    out[idx] = acc;
}

extern "C" void kernel_launch(void* const* d_in, const int* in_sizes, int n_in,
                              void* d_out, int out_size, void* d_ws, size_t ws_size,
                              hipStream_t stream) {
    const int*   ids    = (const int*)d_in[0];
    const float* emb    = (const float*)d_in[1];
    const float* in_w   = (const float*)d_in[2];
    const float* conv_w = (const float*)d_in[3];
    const float* conv_b = (const float*)d_in[4];
    const float* x_w    = (const float*)d_in[5];
    const float* dt_w   = (const float*)d_in[6];
    const float* dt_b   = (const float*)d_in[7];
    const float* a_log  = (const float*)d_in[8];
    const float* d_skip = (const float*)d_in[9];
    const float* out_w  = (const float*)d_in[10];
    const float* norm_w = (const float*)d_in[11];
    const float* norm_f = (const float*)d_in[12];
    const float* lm_w   = (const float*)d_in[13];
    float* out = (float*)d_out;

    // ---- workspace: 42,729,472 bytes (r5/r6-proven budget, exact) ----
    char* ws = (char*)d_ws;
    float* residual = (float*)(ws + 0);            // 4 MB
    float* hn       = (float*)(ws + 4194304);      // 4 MB
    float* xh       = (float*)(ws + 8388608);      // 8 MB (aliased: yb after conv)
    float* zb       = (float*)(ws + 16777216);     // 8 MB
    float* xb       = (float*)(ws + 25165824);     // 8 MB
    float* dbc      = (float*)(ws + 33554432);     // 768 KB
    float* Aprod    = (float*)(ws + 34340864);     // NC*NSC f32 = 4 MB
    float* Hfin     = (float*)(ws + 38535168);     // 4 MB -> end 42,729,472
    float* yb       = xh;

    k_embed<<<(NTOK * 256) / 256, 256, 0, stream>>>(ids, emb, residual);

    for (int i = 0; i < N_LAYER; i++) {
        k_rmsnorm<<<NTOK, 256, 0, stream>>>(residual, norm_w + i * D_MODEL, hn);
        dim3 g1(NTOK / 64, 1024 / 64);
        k_gemm1_tiled<<<g1, 256, 0, stream>>>(hn, in_w + (size_t)i * 1024 * 256, xh, zb);
        k_convxproj<<<NTOK / 16, 256, 0, stream>>>(
            xh, conv_w + (size_t)i * 512 * 4, conv_b + (size_t)i * 512,
            x_w + (size_t)i * 48 * 512, xb, dbc);
        k_scanA<<<(1024 * NC) / 64, 64, 0, stream>>>(
            xb, dbc, dt_w + (size_t)i * 512 * 16, dt_b + (size_t)i * 512,
            a_log + (size_t)i * 512 * 16, Aprod, Hfin);
        k_scanB<<<NSC / 256, 256, 0, stream>>>(Aprod, Hfin);
        k_scanC<<<(1024 * NC) / 64, 64, 0, stream>>>(
            xb, zb, dbc, dt_w + (size_t)i * 512 * 16, dt_b + (size_t)i * 512,
            a_log + (size_t)i * 512 * 16, d_skip + (size_t)i * 512, Hfin, yb);
        dim3 g2(NTOK / 64, 256 / 64);
        k_gemm2_tiled<<<g2, 256, 0, stream>>>(yb, out_w + (size_t)i * 256 * 512, residual);
    }

    k_rmsnorm<<<NTOK, 256, 0, stream>>>(residual, norm_f, hn);
    k_head<<<320, 256, 0, stream>>>(hn, lm_w, out);
}

// Round 12
// 2384.548 us; speedup vs baseline: 2.2462x; 1.2810x over previous
//
#include <hip/hip_runtime.h>
#include <hip/hip_bf16.h>

#define D_MODEL 256
#define N_LAYER 16
#define VOCAB 24
#define D_INNER 512
#define D_STATE 16
#define D_CONV 4
#define DT_RANK 16
#define BATCH 2
#define SEQ 2048
#define NTOK (BATCH*SEQ)   /* 4096 */
#define EPS 1e-5f
#define NC 64              /* scan chunks per sequence */
#define CL (SEQ/NC)        /* 32 tokens per chunk */
#define NSC (BATCH*D_INNER*D_STATE)      /* 16384 scan chains */

typedef __attribute__((ext_vector_type(8))) short short8;
typedef __attribute__((ext_vector_type(4))) float f32x4;

__device__ __forceinline__ float silu(float v) { return v / (1.f + __expf(-v)); }

__device__ __forceinline__ short bfr(float x) {      // f32 -> bf16 RNE
    unsigned u = __float_as_uint(x);
    return (short)((u + 0x7fffu + ((u >> 16) & 1u)) >> 16);
}
__device__ __forceinline__ short8 cvt8(float4 a, float4 b) {
    short8 r;
    r[0] = bfr(a.x); r[1] = bfr(a.y); r[2] = bfr(a.z); r[3] = bfr(a.w);
    r[4] = bfr(b.x); r[5] = bfr(b.y); r[6] = bfr(b.z); r[7] = bfr(b.w);
    return r;
}

// ---------------------------------------------------------------- embedding
__global__ void k_embed(const int* __restrict__ ids, const float* __restrict__ emb,
                        float* __restrict__ residual) {
    int idx = blockIdx.x * 256 + threadIdx.x;      // NTOK*256
    int tok = idx >> 8, c = idx & 255;
    residual[idx] = emb[ids[tok] * D_MODEL + c];
}

// ---------------------------------------------------------------- rmsnorm
__global__ void k_rmsnorm(const float* __restrict__ residual, const float* __restrict__ w,
                          float* __restrict__ hn) {
    __shared__ float red[256];
    int tok = blockIdx.x, c = threadIdx.x;
    float v = residual[tok * 256 + c];
    red[c] = v * v;
    __syncthreads();
    for (int st = 128; st > 0; st >>= 1) {
        if (c < st) red[c] += red[c + st];
        __syncthreads();
    }
    float scale = rsqrtf(red[0] * (1.f / 256.f) + EPS);
    hn[tok * 256 + c] = v * scale * w[c];
}

// ---------------- gemm1 MFMA: [NTOK,256]f32 @ [1024,256]^T f32 -> split x/z
// bf16 conversion during LDS staging; v_mfma_f32_16x16x32_bf16; f32 acc.
__global__ __launch_bounds__(256) void k_gemm1_mfma(const float* __restrict__ A,
                                                    const float* __restrict__ W,
                                                    float* __restrict__ xh,
                                                    float* __restrict__ zb) {
    __shared__ short AsL[64 * 40];   // [row][40] bf16, pad 32->40 (bank-spread)
    __shared__ short WsL[64 * 40];
    const int bm = blockIdx.x * 64, bn = blockIdx.y * 64;
    const int tid = threadIdx.x;
    const int wave = tid >> 6, lane = tid & 63;
    const int wm = (wave & 1) * 32, wn = (wave >> 1) * 32;
    const int quad = lane >> 4, lr = lane & 15;
    const int srow = tid >> 2, skq = (tid & 3) * 8;   // staging: row, k-offset
    f32x4 acc[2][2] = {};
    for (int k0 = 0; k0 < 256; k0 += 32) {
        float4 a0 = *(const float4*)(A + (size_t)(bm + srow) * 256 + k0 + skq);
        float4 a1 = *(const float4*)(A + (size_t)(bm + srow) * 256 + k0 + skq + 4);
        float4 w0 = *(const float4*)(W + (size_t)(bn + srow) * 256 + k0 + skq);
        float4 w1 = *(const float4*)(W + (size_t)(bn + srow) * 256 + k0 + skq + 4);
        __syncthreads();
        *(short8*)&AsL[srow * 40 + skq] = cvt8(a0, a1);
        *(short8*)&WsL[srow * 40 + skq] = cvt8(w0, w1);
        __syncthreads();
        short8 af[2], bf[2];
        #pragma unroll
        for (int i = 0; i < 2; i++) {
            af[i] = *(const short8*)&AsL[(wm + i * 16 + lr) * 40 + quad * 8];
            bf[i] = *(const short8*)&WsL[(wn + i * 16 + lr) * 40 + quad * 8];
        }
        #pragma unroll
        for (int mi = 0; mi < 2; mi++)
            #pragma unroll
            for (int ni = 0; ni < 2; ni++)
                acc[mi][ni] = __builtin_amdgcn_mfma_f32_16x16x32_bf16(
                    af[mi], bf[ni], acc[mi][ni], 0, 0, 0);
    }
    // D mapping: m = quad*4 + reg, n = lane&15 (verified m89)
    #pragma unroll
    for (int mi = 0; mi < 2; mi++) {
        #pragma unroll
        for (int ni = 0; ni < 2; ni++) {
            int gcol = bn + wn + ni * 16 + lr;
            #pragma unroll
            for (int r = 0; r < 4; r++) {
                int grow = bm + wm + mi * 16 + quad * 4 + r;
                float v = acc[mi][ni][r];
                if (bn < 512) xh[(size_t)grow * 512 + gcol] = v;       // uniform branch
                else          zb[(size_t)grow * 512 + gcol - 512] = v;
            }
        }
    }
}

// ---------------- gemm2 MFMA: residual += [NTOK,512] @ [256,512]^T
__global__ __launch_bounds__(256) void k_gemm2_mfma(const float* __restrict__ A,
                                                    const float* __restrict__ W,
                                                    float* __restrict__ residual) {
    __shared__ short AsL[64 * 40];
    __shared__ short WsL[64 * 40];
    const int bm = blockIdx.x * 64, bn = blockIdx.y * 64;
    const int tid = threadIdx.x;
    const int wave = tid >> 6, lane = tid & 63;
    const int wm = (wave & 1) * 32, wn = (wave >> 1) * 32;
    const int quad = lane >> 4, lr = lane & 15;
    const int srow = tid >> 2, skq = (tid & 3) * 8;
    f32x4 acc[2][2] = {};
    for (int k0 = 0; k0 < 512; k0 += 32) {
        float4 a0 = *(const float4*)(A + (size_t)(bm + srow) * 512 + k0 + skq);
        float4 a1 = *(const float4*)(A + (size_t)(bm + srow) * 512 + k0 + skq + 4);
        float4 w0 = *(const float4*)(W + (size_t)(bn + srow) * 512 + k0 + skq);
        float4 w1 = *(const float4*)(W + (size_t)(bn + srow) * 512 + k0 + skq + 4);
        __syncthreads();
        *(short8*)&AsL[srow * 40 + skq] = cvt8(a0, a1);
        *(short8*)&WsL[srow * 40 + skq] = cvt8(w0, w1);
        __syncthreads();
        short8 af[2], bf[2];
        #pragma unroll
        for (int i = 0; i < 2; i++) {
            af[i] = *(const short8*)&AsL[(wm + i * 16 + lr) * 40 + quad * 8];
            bf[i] = *(const short8*)&WsL[(wn + i * 16 + lr) * 40 + quad * 8];
        }
        #pragma unroll
        for (int mi = 0; mi < 2; mi++)
            #pragma unroll
            for (int ni = 0; ni < 2; ni++)
                acc[mi][ni] = __builtin_amdgcn_mfma_f32_16x16x32_bf16(
                    af[mi], bf[ni], acc[mi][ni], 0, 0, 0);
    }
    #pragma unroll
    for (int mi = 0; mi < 2; mi++) {
        #pragma unroll
        for (int ni = 0; ni < 2; ni++) {
            int gcol = bn + wn + ni * 16 + lr;
            #pragma unroll
            for (int r = 0; r < 4; r++) {
                int grow = bm + wm + mi * 16 + quad * 4 + r;
                size_t idx = (size_t)grow * 256 + gcol;
                residual[idx] += acc[mi][ni][r];
            }
        }
    }
}

// ------------- fused depthwise conv + silu + x_proj (16 tokens per block)
__global__ __launch_bounds__(256) void k_convxproj(const float* __restrict__ xh,
                                                   const float* __restrict__ cw,
                                                   const float* __restrict__ cb,
                                                   const float* __restrict__ xw,
                                                   float* __restrict__ xb,
                                                   float* __restrict__ dbc) {
    __shared__ __align__(16) float xcS[16][516];   // pad 4
    const int tok0 = blockIdx.x * 16;              // 16 | 2048 -> no batch crossing
    const int b = tok0 >> 11, l0 = tok0 & 2047;
    const int tid = threadIdx.x;
    #pragma unroll
    for (int dstep = 0; dstep < 2; dstep++) {
        int d = tid + dstep * 256;
        float4 cwv = *(const float4*)(cw + d * 4);
        float cbv = cb[d];
        const float* base = xh + ((size_t)(b << 11)) * 512 + d;
        float xv[19];
        #pragma unroll
        for (int i = 0; i < 19; i++) {
            int lt = l0 - 3 + i;
            xv[i] = (lt >= 0) ? base[(size_t)lt * 512] : 0.f;
        }
        #pragma unroll
        for (int t = 0; t < 16; t++) {
            float acc = cbv + xv[t] * cwv.x + xv[t+1] * cwv.y + xv[t+2] * cwv.z + xv[t+3] * cwv.w;
            float v = silu(acc);
            xcS[t][d] = v;
            xb[(size_t)(tok0 + t) * 512 + d] = v;
        }
    }
    __syncthreads();
    const int tokg = tid >> 4, l = tid & 15;
    #pragma unroll
    for (int j = 0; j < 3; j++) {
        int e = l + j * 16;
        const float4* w4 = (const float4*)(xw + (size_t)e * 512);
        const float4* x4 = (const float4*)&xcS[tokg][0];
        float acc = 0.f;
        #pragma unroll 8
        for (int k4 = 0; k4 < 128; k4++) {
            float4 wv = w4[k4];
            float4 xv = x4[k4];
            acc += xv.x * wv.x + xv.y * wv.y + xv.z * wv.z + xv.w * wv.w;
        }
        dbc[(size_t)(tok0 + tokg) * 48 + e] = acc;
    }
}

// -------- scan phase A: thread = (b,d,chunk); dt fused; 16 s-states in regs
__global__ __launch_bounds__(64) void k_scanA(const float* __restrict__ xb,
                                              const float* __restrict__ dbc,
                                              const float* __restrict__ dtw,
                                              const float* __restrict__ dtb,
                                              const float* __restrict__ a_log,
                                              float* __restrict__ Aprod,
                                              float* __restrict__ Hfin) {
    int gid = blockIdx.x * 64 + threadIdx.x;       // 1024*NC = 65536
    int bd = gid & 1023;
    int c = gid >> 10;
    int d = bd & 511, b = bd >> 9;
    float A[16], h[16], ap[16], wdt[16];
    #pragma unroll
    for (int q = 0; q < 4; q++)
        *(float4*)&wdt[q*4] = *(const float4*)(dtw + d * 16 + q * 4);
    #pragma unroll
    for (int s = 0; s < 16; s++) {
        A[s] = -__expf(a_log[d * 16 + s]);
        h[s] = 0.f; ap[s] = 1.f;
    }
    float bdt = dtb[d];
    int tok0 = b * SEQ + c * CL;
    const float* xp = xb + (size_t)tok0 * 512 + d;
    const float* rp = dbc + (size_t)tok0 * 48;
    for (int t = 0; t < CL; t++) {
        float rv[32];
        #pragma unroll
        for (int q = 0; q < 8; q++) *(float4*)&rv[q*4] = *(const float4*)(rp + t * 48 + q * 4);
        float dtr = bdt;
        #pragma unroll
        for (int r = 0; r < 16; r++) dtr = fmaf(rv[r], wdt[r], dtr);
        float dtv = (dtr > 20.f) ? dtr : __logf(1.f + __expf(dtr));
        float u = dtv * xp[t * 512];
        #pragma unroll
        for (int s = 0; s < 16; s++) {
            float dA = __expf(dtv * A[s]);
            h[s] = fmaf(dA, h[s], u * rv[16 + s]);
            ap[s] *= dA;
        }
    }
    float* Ap = Aprod + (size_t)c * NSC + bd * 16;
    float* Hp = Hfin  + (size_t)c * NSC + bd * 16;
    #pragma unroll
    for (int q = 0; q < 4; q++) {
        *(float4*)(Ap + q * 4) = make_float4(ap[q*4], ap[q*4+1], ap[q*4+2], ap[q*4+3]);
        *(float4*)(Hp + q * 4) = make_float4(h[q*4], h[q*4+1], h[q*4+2], h[q*4+3]);
    }
}

// ---------------- scan phase B: serial combine over chunks (in place)
__global__ void k_scanB(const float* __restrict__ Aprod, float* __restrict__ Hfin) {
    int chain = blockIdx.x * 256 + threadIdx.x;    // NSC
    float h = 0.f;
    for (int c = 0; c < NC; c++) {
        int i = c * NSC + chain;
        float a = Aprod[i], f = Hfin[i];
        Hfin[i] = h;
        h = a * h + f;
    }
}

// -------- scan phase C: rescan from start state (dt fused), gate -> y
__global__ __launch_bounds__(64) void k_scanC(const float* __restrict__ xb,
                                              const float* __restrict__ zb,
                                              const float* __restrict__ dbc,
                                              const float* __restrict__ dtw,
                                              const float* __restrict__ dtb,
                                              const float* __restrict__ a_log,
                                              const float* __restrict__ Dp,
                                              const float* __restrict__ Hstart,
                                              float* __restrict__ yb) {
    int gid = blockIdx.x * 64 + threadIdx.x;       // 65536
    int bd = gid & 1023;
    int c = gid >> 10;
    int d = bd & 511, b = bd >> 9;
    float A[16], h[16], wdt[16];
    #pragma unroll
    for (int q = 0; q < 4; q++)
        *(float4*)&wdt[q*4] = *(const float4*)(dtw + d * 16 + q * 4);
    const float* Hp = Hstart + (size_t)c * NSC + bd * 16;
    #pragma unroll
    for (int s = 0; s < 16; s++) {
        A[s] = -__expf(a_log[d * 16 + s]);
        h[s] = Hp[s];
    }
    float bdt = dtb[d];
    float Dv = Dp[d];
    int tok0 = b * SEQ + c * CL;
    const float* xp = xb + (size_t)tok0 * 512 + d;
    const float* zp = zb + (size_t)tok0 * 512 + d;
    const float* rp = dbc + (size_t)tok0 * 48;
    float* yp = yb + (size_t)tok0 * 512 + d;
    for (int t = 0; t < CL; t++) {
        float rv[48];
        #pragma unroll
        for (int q = 0; q < 12; q++) *(float4*)&rv[q*4] = *(const float4*)(rp + t * 48 + q * 4);
        float dtr = bdt;
        #pragma unroll
        for (int r = 0; r < 16; r++) dtr = fmaf(rv[r], wdt[r], dtr);
        float dtv = (dtr > 20.f) ? dtr : __logf(1.f + __expf(dtr));
        float xv = xp[t * 512];
        float u = dtv * xv;
        float sum = 0.f;
        #pragma unroll
        for (int s = 0; s < 16; s++) {
            float dA = __expf(dtv * A[s]);
            h[s] = fmaf(dA, h[s], u * rv[16 + s]);
            sum = fmaf(h[s], rv[32 + s], sum);
        }
        float zv = zp[t * 512];
        yp[t * 512] = (sum + Dv * xv) * silu(zv);
    }
}

// ---------------------------------------------------------------- lm head
__global__ void k_head(const float* __restrict__ hn, const float* __restrict__ lw,
                       float* __restrict__ out) {
    int idx = blockIdx.x * 256 + threadIdx.x;      // NTOK*20 = 81920
    int tok = idx / 20, v = idx % 20;
    const float* a = hn + (size_t)tok * 256;
    const float* w = lw + (size_t)v * 256;
    float acc = 0.f;
    for (int k = 0; k < 256; k++) acc += a[k] * w[k];
    out[idx] = acc;
}

extern "C" void kernel_launch(void* const* d_in, const int* in_sizes, int n_in,
                              void* d_out, int out_size, void* d_ws, size_t ws_size,
                              hipStream_t stream) {
    const int*   ids    = (const int*)d_in[0];
    const float* emb    = (const float*)d_in[1];
    const float* in_w   = (const float*)d_in[2];
    const float* conv_w = (const float*)d_in[3];
    const float* conv_b = (const float*)d_in[4];
    const float* x_w    = (const float*)d_in[5];
    const float* dt_w   = (const float*)d_in[6];
    const float* dt_b   = (const float*)d_in[7];
    const float* a_log  = (const float*)d_in[8];
    const float* d_skip = (const float*)d_in[9];
    const float* out_w  = (const float*)d_in[10];
    const float* norm_w = (const float*)d_in[11];
    const float* norm_f = (const float*)d_in[12];
    const float* lm_w   = (const float*)d_in[13];
    float* out = (float*)d_out;

    // ---- workspace: 42,729,472 bytes (r5/r6-proven budget, exact) ----
    char* ws = (char*)d_ws;
    float* residual = (float*)(ws + 0);            // 4 MB
    float* hn       = (float*)(ws + 4194304);      // 4 MB
    float* xh       = (float*)(ws + 8388608);      // 8 MB (aliased: yb after conv)
    float* zb       = (float*)(ws + 16777216);     // 8 MB
    float* xb       = (float*)(ws + 25165824);     // 8 MB
    float* dbc      = (float*)(ws + 33554432);     // 768 KB
    float* Aprod    = (float*)(ws + 34340864);     // NC*NSC f32 = 4 MB
    float* Hfin     = (float*)(ws + 38535168);     // 4 MB -> end 42,729,472
    float* yb       = xh;

    k_embed<<<(NTOK * 256) / 256, 256, 0, stream>>>(ids, emb, residual);

    for (int i = 0; i < N_LAYER; i++) {
        k_rmsnorm<<<NTOK, 256, 0, stream>>>(residual, norm_w + i * D_MODEL, hn);
        dim3 g1(NTOK / 64, 1024 / 64);
        k_gemm1_mfma<<<g1, 256, 0, stream>>>(hn, in_w + (size_t)i * 1024 * 256, xh, zb);
        k_convxproj<<<NTOK / 16, 256, 0, stream>>>(
            xh, conv_w + (size_t)i * 512 * 4, conv_b + (size_t)i * 512,
            x_w + (size_t)i * 48 * 512, xb, dbc);
        k_scanA<<<(1024 * NC) / 64, 64, 0, stream>>>(
            xb, dbc, dt_w + (size_t)i * 512 * 16, dt_b + (size_t)i * 512,
            a_log + (size_t)i * 512 * 16, Aprod, Hfin);
        k_scanB<<<NSC / 256, 256, 0, stream>>>(Aprod, Hfin);
        k_scanC<<<(1024 * NC) / 64, 64, 0, stream>>>(
            xb, zb, dbc, dt_w + (size_t)i * 512 * 16, dt_b + (size_t)i * 512,
            a_log + (size_t)i * 512 * 16, d_skip + (size_t)i * 512, Hfin, yb);
        dim3 g2(NTOK / 64, 256 / 64);
        k_gemm2_mfma<<<g2, 256, 0, stream>>>(yb, out_w + (size_t)i * 256 * 512, residual);
    }

    k_rmsnorm<<<NTOK, 256, 0, stream>>>(residual, norm_f, hn);
    k_head<<<320, 256, 0, stream>>>(hn, lm_w, out);
}